// Round 10
// baseline (1221.316 us; speedup 1.0000x reference)
//
#include <hip/hip_runtime.h>
#include <hip/hip_bf16.h>
#include <math.h>

#define N_NODES 100000
#define N_EDGES 1000000
#define F_IN    128
#define ED_DIM  16
#define H_HEADS 5
#define C_CH    16
#define HC      80
#define NEG_SLOPE 0.2f

#define SCAN_B 256
#define SCAN_G ((N_NODES + SCAN_B - 1) / SCAN_B)   // 391
#define DBIN 64
#define EPAD 8   // padding entries on src_s/perm; 8 pad rows on eattr_s

typedef float v2f __attribute__((ext_vector_type(2)));

// ================= CSR build (graph is static across layers) =================

__global__ void k_hist(const int* __restrict__ dst, int* __restrict__ count) {
    const int e = blockIdx.x * 256 + threadIdx.x;
    if (e < N_EDGES) atomicAdd(count + dst[e], 1);
}

__global__ __launch_bounds__(SCAN_B) void k_part(const int* __restrict__ count,
                                                 int* __restrict__ partial) {
    const int i = blockIdx.x * SCAN_B + threadIdx.x;
    int v = (i < N_NODES) ? count[i] : 0;
    const int lane = threadIdx.x & 63;
    const int w    = threadIdx.x >> 6;
    __shared__ int ws[SCAN_B / 64];
    #pragma unroll
    for (int o = 32; o > 0; o >>= 1) v += __shfl_down(v, o, 64);
    if (lane == 0) ws[w] = v;
    __syncthreads();
    if (threadIdx.x == 0) {
        int s = 0;
        #pragma unroll
        for (int k = 0; k < SCAN_B / 64; ++k) s += ws[k];
        partial[blockIdx.x] = s;
    }
}

__global__ __launch_bounds__(512) void k_scanp(const int* __restrict__ partial,
                                               int* __restrict__ blockoff,
                                               int* __restrict__ rowstart) {
    __shared__ int s[512];
    const int t = threadIdx.x;
    int v = (t < SCAN_G) ? partial[t] : 0;
    s[t] = v;
    __syncthreads();
    for (int o = 1; o < 512; o <<= 1) {
        int u = (t >= o) ? s[t - o] : 0;
        __syncthreads();
        s[t] += u;
        __syncthreads();
    }
    if (t < SCAN_G) blockoff[t] = (t == 0) ? 0 : s[t - 1];
    if (t == 0) rowstart[N_NODES] = s[511];
}

__global__ __launch_bounds__(SCAN_B) void k_apply(const int* __restrict__ count,
                                                  const int* __restrict__ blockoff,
                                                  int* __restrict__ rowstart) {
    __shared__ int s[SCAN_B];
    const int i = blockIdx.x * SCAN_B + threadIdx.x;
    const int t = threadIdx.x;
    const int v = (i < N_NODES) ? count[i] : 0;
    s[t] = v;
    __syncthreads();
    for (int o = 1; o < SCAN_B; o <<= 1) {
        int u = (t >= o) ? s[t - o] : 0;
        __syncthreads();
        s[t] += u;
        __syncthreads();
    }
    if (i < N_NODES) rowstart[i] = blockoff[blockIdx.x] + (s[t] - v);
}

// place edge into CSR slot; src_s stores src*HC (pre-scaled for the hot loop);
// if COPY, also copy the 64B eattr row into CSR order (fused permea)
template<bool COPY>
__global__ void k_place(const int* __restrict__ src, const int* __restrict__ dst,
                        const int* __restrict__ rowstart, int* __restrict__ cursor,
                        int* __restrict__ perm, int* __restrict__ src_s,
                        const float* __restrict__ eattr, float* __restrict__ eattr_s) {
    const int e = blockIdx.x * 256 + threadIdx.x;
    if (e >= N_EDGES) return;
    const int d = dst[e];
    const int pos = rowstart[d] + atomicAdd(cursor + d, 1);
    src_s[pos] = src[e] * HC;
    if (COPY) {
        const float4* s4 = (const float4*)(eattr + (size_t)e * ED_DIM);
        float4* d4 = (float4*)(eattr_s + (size_t)pos * ED_DIM);
        d4[0] = s4[0]; d4[1] = s4[1]; d4[2] = s4[2]; d4[3] = s4[3];
    } else {
        perm[pos] = e;
    }
}

// ====== degree-bucket counting sort of nodes (descending degree) =============
__global__ __launch_bounds__(256) void k_deghist(const int* __restrict__ cnt,
                                                 int* __restrict__ dhist) {
    __shared__ int lh[DBIN];
    const int t = threadIdx.x;
    if (t < DBIN) lh[t] = 0;
    __syncthreads();
    const int n = blockIdx.x * 256 + t;
    if (n < N_NODES) atomicAdd(&lh[min(cnt[n], DBIN - 1)], 1);
    __syncthreads();
    if (t < DBIN && lh[t] > 0) atomicAdd(dhist + t, lh[t]);
}

// also zeroes the perm/src_s padding (ws is re-poisoned before every launch)
__global__ void k_degoff(const int* __restrict__ dhist, int* __restrict__ dcur,
                         int* __restrict__ perm, int* __restrict__ src_s) {
    if (threadIdx.x == 0) {
        int off = 0;
        for (int b = DBIN - 1; b >= 0; --b) { dcur[b] = off; off += dhist[b]; }
        for (int i = 0; i < EPAD; ++i) {
            perm[N_EDGES + i]  = 0;
            src_s[N_EDGES + i] = 0;
        }
    }
}

__global__ __launch_bounds__(256) void k_degplace(const int* __restrict__ cnt,
                                                  int* __restrict__ dcur,
                                                  int* __restrict__ nodeord) {
    __shared__ int lh[DBIN];
    __shared__ int base[DBIN];
    const int t = threadIdx.x;
    if (t < DBIN) lh[t] = 0;
    __syncthreads();
    const int n = blockIdx.x * 256 + t;
    int b = 0, r = 0;
    if (n < N_NODES) {
        b = min(cnt[n], DBIN - 1);
        r = atomicAdd(&lh[b], 1);
    }
    __syncthreads();
    if (t < DBIN && lh[t] > 0) base[t] = atomicAdd(dcur + t, lh[t]);
    __syncthreads();
    if (n < N_NODES) nodeord[base[b] + r] = n;
}

// ====== fused dual node transform v3: 128-node tile, 8n x 4j per thread =====
// Fewer LDS b128 reads per FMA than the 64-node tile (4 reads / 64 FMAs):
// the old 4x4 tile was ds_read-bound. Node groups at +0/+64 keep the
// conflict-free (2-way) bank pattern of stride-4 float4 reads.
template<int DIN>
__global__ __launch_bounds__(320) void k_xform3(
    const float* __restrict__ A,
    const float* __restrict__ WL, const float* __restrict__ bL,
    const float* __restrict__ WR, const float* __restrict__ bR,
    float* __restrict__ outL, float* __restrict__ outR, int nn) {
    __shared__ float As[16][132];   // [k][node 0..127], +4 pad
    __shared__ float WsL[16][80];
    __shared__ float WsR[16][80];
    const int t  = threadIdx.x;
    const int n0 = blockIdx.x * 128;
    const int tn = (t & 15) * 4;    // nodes tn..tn+3 and tn+64..tn+67
    const int tj = (t >> 4) * 4;    // j offset (0..76)
    float4 accL[8], accR[8];
    #pragma unroll
    for (int u = 0; u < 8; ++u) {
        accL[u] = make_float4(0.f, 0.f, 0.f, 0.f);
        accR[u] = make_float4(0.f, 0.f, 0.f, 0.f);
    }

    for (int k0 = 0; k0 < DIN; k0 += 16) {
        __syncthreads();
        for (int i = t; i < 128*16; i += 320) {
            int nl = i >> 4, kk = i & 15;
            int n = n0 + nl;
            As[kk][nl] = (n < nn) ? A[(size_t)n*DIN + k0 + kk] : 0.f;
        }
        for (int i = t; i < 80*16; i += 320) {
            int jj = i >> 4, kk = i & 15;
            WsL[kk][jj] = WL[(size_t)jj*DIN + k0 + kk];
            WsR[kk][jj] = WR[(size_t)jj*DIN + k0 + kk];
        }
        __syncthreads();
        #pragma unroll
        for (int k = 0; k < 16; ++k) {
            const float4 av0 = *(const float4*)&As[k][tn];
            const float4 av1 = *(const float4*)&As[k][tn + 64];
            const float4 wl  = *(const float4*)&WsL[k][tj];
            const float4 wr  = *(const float4*)&WsR[k][tj];
            const float a[8] = {av0.x, av0.y, av0.z, av0.w, av1.x, av1.y, av1.z, av1.w};
            #pragma unroll
            for (int u = 0; u < 8; ++u) {
                accL[u].x += a[u]*wl.x; accL[u].y += a[u]*wl.y;
                accL[u].z += a[u]*wl.z; accL[u].w += a[u]*wl.w;
                accR[u].x += a[u]*wr.x; accR[u].y += a[u]*wr.y;
                accR[u].z += a[u]*wr.z; accR[u].w += a[u]*wr.w;
            }
        }
    }
    const float4 bvL = *(const float4*)(bL + tj);
    const float4 bvR = *(const float4*)(bR + tj);
    #pragma unroll
    for (int u = 0; u < 8; ++u) {
        const int n = n0 + tn + ((u < 4) ? u : (60 + u));   // +0..3, +64..67
        if (n < nn) {
            float4 o;
            o.x = accL[u].x + bvL.x; o.y = accL[u].y + bvL.y;
            o.z = accL[u].z + bvL.z; o.w = accL[u].w + bvL.w;
            *(float4*)(outL + (size_t)n*HC + tj) = o;
            o.x = accR[u].x + bvR.x; o.y = accR[u].y + bvR.y;
            o.z = accR[u].z + bvR.z; o.w = accR[u].w + bvR.w;
            *(float4*)(outR + (size_t)n*HC + tj) = o;
        }
    }
}

// cross-lane helpers: compile-time ds_swizzle, zero VALU overhead
#define SWZ(v, imm) __int_as_float(__builtin_amdgcn_ds_swizzle(__float_as_int(v), (imm)))
// broadcast lane ((lane&0x10)|j) within each 32-lane half: imm = (j<<5)|0x10
#define BC(v, j) SWZ(v, ((j) << 5) | 0x10)

__device__ __forceinline__ v2f mk2(float a, float b) { v2f r; r.x = a; r.y = b; return r; }
#define BC2(a, b, j) mk2(BC(a, j), BC(b, j))

// packed per-pair logit+exp+accumulate; slot0 always valid, slot1 gated
__device__ __forceinline__ void pair_step(
    float ea0, float ea1, float xl0, float xl1, float xrc, float attc,
    const float4& w0, const float4& w1, const float4& w2, const float4& w3,
    float g1, v2f& acc, v2f& l) {
    v2f m0 = w0.x * BC2(ea0, ea1, 0)  + w0.y * BC2(ea0, ea1, 1)
           + w0.z * BC2(ea0, ea1, 2)  + w0.w * BC2(ea0, ea1, 3);
    v2f m1 = w1.x * BC2(ea0, ea1, 4)  + w1.y * BC2(ea0, ea1, 5)
           + w1.z * BC2(ea0, ea1, 6)  + w1.w * BC2(ea0, ea1, 7);
    v2f m2 = w2.x * BC2(ea0, ea1, 8)  + w2.y * BC2(ea0, ea1, 9)
           + w2.z * BC2(ea0, ea1, 10) + w2.w * BC2(ea0, ea1, 11);
    v2f m3 = w3.x * BC2(ea0, ea1, 12) + w3.y * BC2(ea0, ea1, 13)
           + w3.z * BC2(ea0, ea1, 14) + w3.w * BC2(ea0, ea1, 15);
    v2f xlv = mk2(xl0, xl1);
    v2f v = xlv + xrc + ((m0 + m1) + (m2 + m3));
    v2f vp = mk2(fmaxf(v.x, 0.f), fmaxf(v.y, 0.f));
    v2f vn = mk2(fminf(v.x, 0.f), fminf(v.y, 0.f));
    v = (vp + NEG_SLOPE * vn) * attc;
    v += mk2(SWZ(v.x, 0x041F), SWZ(v.y, 0x041F));
    v += mk2(SWZ(v.x, 0x081F), SWZ(v.y, 0x081F));
    v += mk2(SWZ(v.x, 0x101F), SWZ(v.y, 0x101F));
    v += mk2(SWZ(v.x, 0x201F), SWZ(v.y, 0x201F));
    v2f pt = mk2(__expf(v.x), __expf(v.y) * g1);
    acc += pt * xlv;
    l   += pt;
}

// ====== fused attention v6: packed pairs, 2-pair software pipeline ==========
// thread = channel c (head = c>>4), 1 node per 80-thread group. Pads make all
// prefetches in-bounds; pad garbage is bounded (exp finite) and gated to 0.
template<bool SORTED>
__global__ __launch_bounds__(320) void k_fused6(
    const float* __restrict__ xl, const float* __restrict__ xr,
    const float* __restrict__ ea,   // eattr_s if SORTED, raw eattr otherwise
    const float* __restrict__ we, const float* __restrict__ att,
    const int* __restrict__ perm, const int* __restrict__ src_s,
    const int* __restrict__ rowstart, const int* __restrict__ nodeord,
    const float* __restrict__ bias, float* __restrict__ out, int relu) {
    const int t = threadIdx.x;
    const int group = t / 80;
    const int c = t - group * 80;
    const int idx = blockIdx.x * 4 + group;
    if (idx >= N_NODES) return;
    const int n = nodeord[idx];

    const float4* w4 = (const float4*)(we + c * ED_DIM);
    const float4 w0 = w4[0], w1 = w4[1], w2 = w4[2], w3 = w4[3];
    const float attc = att[c];
    const float bc   = bias[c];
    const float xrc  = xr[n * HC + c];
    const int lane16 = c & 15;

    const int rs = rowstart[n], re = rowstart[n + 1];
    float accs = 0.f, ls = 0.f;

    if (rs < re) {
        // pipeline: cur pair (p,p+1) + nxt pair (p+2,p+3) resident; issue p+4
        const int o0 = src_s[rs],     o1 = src_s[rs + 1];
        const int o2 = src_s[rs + 2], o3 = src_s[rs + 3];
        float xc0 = xl[o0 + c], xc1 = xl[o1 + c];
        float xn0 = xl[o2 + c], xn1 = xl[o3 + c];
        int s4 = src_s[rs + 4], s5 = src_s[rs + 5];
        const int ec0 = SORTED ? rs       : perm[rs];
        const int ec1 = SORTED ? (rs + 1) : perm[rs + 1];
        const int ed0 = SORTED ? (rs + 2) : perm[rs + 2];
        const int ed1 = SORTED ? (rs + 3) : perm[rs + 3];
        float ac0 = ea[ec0 * ED_DIM + lane16], ac1 = ea[ec1 * ED_DIM + lane16];
        float an0 = ea[ed0 * ED_DIM + lane16], an1 = ea[ed1 * ED_DIM + lane16];

        v2f acc = mk2(0.f, 0.f), l = mk2(0.f, 0.f);
        for (int p = rs; p < re; p += 2) {
            const float e0 = ac0, e1 = ac1, x0 = xc0, x1 = xc1;
            ac0 = an0; ac1 = an1; xc0 = xn0; xc1 = xn1;
            // issue loads for pair p+4 (land next iteration)
            xn0 = xl[s4 + c];
            xn1 = xl[s5 + c];
            s4 = src_s[p + 6];
            s5 = src_s[p + 7];
            const int f0 = SORTED ? (p + 4) : perm[p + 4];
            const int f1 = SORTED ? (p + 5) : perm[p + 5];
            an0 = ea[f0 * ED_DIM + lane16];
            an1 = ea[f1 * ED_DIM + lane16];

            const float g1 = (p + 1 < re) ? 1.f : 0.f;
            pair_step(e0, e1, x0, x1, xrc, attc, w0, w1, w2, w3, g1, acc, l);
        }
        accs = acc.x + acc.y;
        ls   = l.x + l.y;
    }
    float o = accs / (ls + 1e-16f) + bc;
    if (relu) o = fmaxf(o, 0.f);
    out[n * HC + c] = o;
}

extern "C" void kernel_launch(void* const* d_in, const int* in_sizes, int n_in,
                              void* d_out, int out_size, void* d_ws, size_t ws_size,
                              hipStream_t stream) {
    (void)in_sizes; (void)n_in; (void)out_size;
    const float* x     = (const float*)d_in[0];
    const int*   ei    = (const int*)d_in[1];
    const float* eattr = (const float*)d_in[2];
    const int* srcp = ei;
    const int* dstp = ei + N_EDGES;

    // workspace layout
    float* h      = (float*)d_ws;                            // N*80
    float* xl     = h  + (size_t)N_NODES*HC;                 // N*80
    float* xr     = xl + (size_t)N_NODES*HC;                 // N*80
    int* rowstart = (int*)(xr + (size_t)N_NODES*HC);         // N+1
    int* cursor   = rowstart + (N_NODES + 1);                // N
    int* perm     = cursor + N_NODES;                        // E + EPAD
    int* src_s    = perm + N_EDGES + EPAD;                   // E + EPAD
    int* partial  = src_s + N_EDGES + EPAD;                  // SCAN_G
    int* blockoff = partial + SCAN_G;                        // SCAN_G
    int* dhist    = blockoff + SCAN_G;                       // DBIN
    int* dcur     = dhist + DBIN;                            // DBIN
    int* nodeord  = dcur + DBIN;                             // N
    float* eattr_s = (float*)(nodeord + N_NODES);            // (E+EPAD)*16 (optional)
    float* outp   = (float*)d_out;

    const size_t need_sorted =
        (size_t)((char*)(eattr_s + (size_t)(N_EDGES + EPAD) * ED_DIM) - (char*)d_ws);
    const bool use_sorted = (ws_size >= need_sorted);

    const dim3 bx(320);
    const dim3 gx((N_NODES + 127) / 128);
    const dim3 gf((N_NODES + 3) / 4);
    const dim3 geb((N_EDGES + 255) / 256);
    const dim3 gnb((N_NODES + 255) / 256);

    // ---- build CSR by destination + degree-sorted node order (once) ----
    hipMemsetAsync(cursor, 0, (size_t)N_NODES * sizeof(int), stream);
    hipMemsetAsync(dhist, 0, DBIN * sizeof(int), stream);
    k_hist<<<geb, 256, 0, stream>>>(dstp, cursor);
    k_part<<<SCAN_G, SCAN_B, 0, stream>>>(cursor, partial);
    k_scanp<<<1, 512, 0, stream>>>(partial, blockoff, rowstart);
    k_apply<<<SCAN_G, SCAN_B, 0, stream>>>(cursor, blockoff, rowstart);
    k_deghist<<<gnb, 256, 0, stream>>>(cursor, dhist);
    k_degoff<<<1, 64, 0, stream>>>(dhist, dcur, perm, src_s);
    k_degplace<<<gnb, 256, 0, stream>>>(cursor, dcur, nodeord);
    hipMemsetAsync(cursor, 0, (size_t)N_NODES * sizeof(int), stream);
    if (use_sorted) {
        k_place<true><<<geb, 256, 0, stream>>>(srcp, dstp, rowstart, cursor,
                                               perm, src_s, eattr, eattr_s);
    } else {
        k_place<false><<<geb, 256, 0, stream>>>(srcp, dstp, rowstart, cursor,
                                                perm, src_s, eattr, eattr_s);
    }

    for (int L = 0; L < 3; ++L) {
        const float* in   = (L == 0) ? x : h;
        float*       oacc = (L == 2) ? outp : h;
        const float* wl   = (const float*)d_in[3 + L*7 + 0];
        const float* bl   = (const float*)d_in[3 + L*7 + 1];
        const float* wr   = (const float*)d_in[3 + L*7 + 2];
        const float* br   = (const float*)d_in[3 + L*7 + 3];
        const float* we   = (const float*)d_in[3 + L*7 + 4];
        const float* att  = (const float*)d_in[3 + L*7 + 5];
        const float* bias = (const float*)d_in[3 + L*7 + 6];

        if (L == 0) {
            k_xform3<F_IN><<<gx, bx, 0, stream>>>(in, wl, bl, wr, br, xl, xr, N_NODES);
        } else {
            k_xform3<HC><<<gx, bx, 0, stream>>>(in, wl, bl, wr, br, xl, xr, N_NODES);
        }
        if (use_sorted) {
            k_fused6<true><<<gf, bx, 0, stream>>>(xl, xr, eattr_s, we, att, perm,
                                                  src_s, rowstart, nodeord, bias,
                                                  oacc, (L < 2) ? 1 : 0);
        } else {
            k_fused6<false><<<gf, bx, 0, stream>>>(xl, xr, eattr, we, att, perm,
                                                   src_s, rowstart, nodeord, bias,
                                                   oacc, (L < 2) ? 1 : 0);
        }
    }
}